// Round 6
// baseline (507.164 us; speedup 1.0000x reference)
//
#include <hip/hip_runtime.h>
#include <cstdint>
#include <cstddef>

typedef float  f32x4 __attribute__((ext_vector_type(4)));
typedef float  f32x2 __attribute__((ext_vector_type(2)));
typedef short  s16x8 __attribute__((ext_vector_type(8)));
typedef short  s16x4 __attribute__((ext_vector_type(4)));
typedef unsigned int u32x4 __attribute__((ext_vector_type(4)));

#define EPSV 1e-5f

__device__ __forceinline__ float rfl(float v) {
  return __builtin_bit_cast(float, __builtin_amdgcn_readfirstlane(__builtin_bit_cast(int, v)));
}
__device__ __forceinline__ unsigned pk2(float a, float b) {
  unsigned short ua = __builtin_bit_cast(unsigned short, (__bf16)a);
  unsigned short ub = __builtin_bit_cast(unsigned short, (__bf16)b);
  return (unsigned)ua | ((unsigned)ub << 16);
}
__device__ __forceinline__ void gll16(const void* g, void* l) {
  __builtin_amdgcn_global_load_lds((const __attribute__((address_space(1))) unsigned int*)g,
                                   (__attribute__((address_space(3))) unsigned int*)l, 16, 0, 0);
}

// ---------------- kernel F: fold BN-o into Wo, emit bf16 in fragment layout ----------------
__global__ void kF(const float* __restrict__ wo, const float* __restrict__ bo,
                   const float* __restrict__ go, const float* __restrict__ beo,
                   const float* __restrict__ mo, const float* __restrict__ vo,
                   __bf16* __restrict__ wopp, float* __restrict__ co)
{
  const int oc = blockIdx.x;   // 0..511
  const int k  = threadIdx.x;  // 0..511
  float invo = go[oc] * rsqrtf(vo[oc] + EPSV);
  float v = wo[(size_t)oc*512 + k] * invo;
  int mt = oc >> 7, ocl = oc & 127;
  int kt = k >> 6, kk = (k >> 5) & 1, g = (k >> 3) & 3, jj = k & 7;
  size_t dst = (size_t)(mt*8 + kt)*10240 + (size_t)kk*5120 + ocl*40 + g*8 + jj;
  wopp[dst] = (__bf16)v;
  if (k == 0) co[oc] = bo[oc]*invo + beo[oc] - mo[oc]*invo;
}

// ---------------- kernel A: 4 dilated depthwise convs + BN + ReLU + 4x4 mix + BN + ReLU ----
// block = (b,c), full plane. LDS: 132 rows x 118 f32 (row = 18 zero-pad | 96 data | 4 zero
// slack), 18 zero rows top/bottom -> NO masks, NO range checks (right overflow of row L
// falls into row L+1's zero pad). Stride 118 dwords == 22 mod 32 -> b64 reads at bank floor.
// Thread = 12 px (8 colg x 96 rows); all tap reads = 1 base VGPR + immediate ds offsets.
__global__ __launch_bounds__(768, 6) void kA(const float* __restrict__ x,
    const float* __restrict__ wdw, const float* __restrict__ bdw, const float* __restrict__ gdw,
    const float* __restrict__ bedw, const float* __restrict__ mdw, const float* __restrict__ vdw,
    const float* __restrict__ w4, const float* __restrict__ bsc, const float* __restrict__ gsc,
    const float* __restrict__ besc, const float* __restrict__ msc, const float* __restrict__ vsc,
    __bf16* __restrict__ z2s)
{
  __shared__ alignas(16) float sp[15596];       // 132*118 + 20 = 62384 B
  const int tid = threadIdx.x;
  const int b = blockIdx.x >> 7, c = blockIdx.x & 127;

  // uniform folded params (readfirstlane -> SGPRs)
  float wf[4][9], cdwv[4], w4f[4][4], c4v[4];
  #pragma unroll
  for (int i = 0; i < 4; ++i) {
    int idx = i*128 + c;
    float inv = gdw[idx] * rsqrtf(vdw[idx] + EPSV);
    #pragma unroll
    for (int t = 0; t < 9; ++t) wf[i][t] = rfl(wdw[(size_t)idx*9 + t] * inv);
    cdwv[i] = rfl(bdw[idx]*inv + bedw[idx] - mdw[idx]*inv);
  }
  #pragma unroll
  for (int o = 0; o < 4; ++o) {
    float invs = gsc[o] * rsqrtf(vsc[o] + EPSV);
    #pragma unroll
    for (int i = 0; i < 4; ++i) w4f[o][i] = rfl(w4[o*4 + i] * invs);
    c4v[o] = rfl(bsc[o]*invs + besc[o] - msc[o]*invs);
  }

  { // zero the whole buffer once (stage phases only write interior cols -> pads persist)
    f32x2* spv = (f32x2*)sp;
    #pragma unroll
    for (int z = 0; z < 11; ++z) {
      int idx = tid + z*768;
      if (idx < 7798) spv[idx] = (f32x2){0.f, 0.f};
    }
  }

  const int colg = tid & 7, row = tid >> 3;     // compute coords: 12 px, one row
  const int w0 = colg * 12;
  const int jc = tid % 24, jr = tid / 24;       // stage coords (rows jr, jr+32, jr+64)
  const f32x4* xv = (const f32x4*)x;
  const size_t gbase = (size_t)(b*512 + c) * 2304;

  float zacc[4][12];
  #pragma unroll
  for (int o = 0; o < 4; ++o)
    #pragma unroll
    for (int j = 0; j < 12; ++j) zacc[o][j] = c4v[o];

  const float* base = sp + row*118 + w0;        // min tap idx: row h-18 -> LDS row h

  const int RR[4] = {1, 6, 12, 18};
  #pragma unroll
  for (int i = 0; i < 4; ++i) {
    const int r = RR[i];
    __syncthreads();                            // buffer free (zero done / prev compute done)
    #pragma unroll
    for (int k = 0; k < 3; ++k) {               // stage plane i: 3 f32x4 per thread
      f32x4 v = xv[gbase + (size_t)i*294912 + (size_t)((jr + k*32)*24 + jc)];
      float* d = sp + (18 + jr + k*32)*118 + 18 + jc*4;   // 8B-aligned
      *(f32x2*)(d)     = (f32x2){v.x, v.y};
      *(f32x2*)(d + 2) = (f32x2){v.z, v.w};
    }
    __syncthreads();                            // plane ready

    float acc[12];
    #pragma unroll
    for (int j = 0; j < 12; ++j) acc[j] = 0.f;

    #pragma unroll
    for (int d = 0; d < 3; ++d) {               // dh = d-1; all offsets compile-time
      const int R0 = (18 + (d-1)*r)*118 + 18;   // rel f32 offset of col w0 at tap row
      const float wl = wf[i][d*3], wc = wf[i][d*3+1], wr = wf[i][d*3+2];
      if (i == 0) {                              // r=1: one 16-f32 span
        float s[16];
        #pragma unroll
        for (int t = 0; t < 8; ++t) *(f32x2*)(s + 2*t) = *(const f32x2*)(base + R0 - 2 + 2*t);
        #pragma unroll
        for (int j = 0; j < 12; ++j)
          acc[j] += wl*s[j+1] + wc*s[j+2] + wr*s[j+3];
      } else {                                   // even r: 3 disjoint 12-f32 windows, rolled
        float t[12];
        #pragma unroll
        for (int t2 = 0; t2 < 6; ++t2) *(f32x2*)(t + 2*t2) = *(const f32x2*)(base + R0 - r + 2*t2);
        #pragma unroll
        for (int j = 0; j < 12; ++j) acc[j] += wl*t[j];
        #pragma unroll
        for (int t2 = 0; t2 < 6; ++t2) *(f32x2*)(t + 2*t2) = *(const f32x2*)(base + R0 + 2*t2);
        #pragma unroll
        for (int j = 0; j < 12; ++j) acc[j] += wc*t[j];
        #pragma unroll
        for (int t2 = 0; t2 < 6; ++t2) *(f32x2*)(t + 2*t2) = *(const f32x2*)(base + R0 + r + 2*t2);
        #pragma unroll
        for (int j = 0; j < 12; ++j) acc[j] += wr*t[j];
      }
    }
    #pragma unroll
    for (int j = 0; j < 12; ++j) {
      float y = fmaxf(acc[j] + cdwv[i], 0.f);
      #pragma unroll
      for (int o = 0; o < 4; ++o) zacc[o][j] += w4f[o][i]*y;
    }
  }

  // finalize + store: [pix][o]; thread owns 3 quads = 96 B contiguous
  float z0[12], z1[12], z2[12], z3[12];
  #pragma unroll
  for (int j = 0; j < 12; ++j) {
    z0[j] = fmaxf(zacc[0][j], 0.f);
    z1[j] = fmaxf(zacc[1][j], 0.f);
    z2[j] = fmaxf(zacc[2][j], 0.f);
    z3[j] = fmaxf(zacc[3][j], 0.f);
  }
  __bf16* zb = z2s + (size_t)(b*128 + c)*36864 + (size_t)(row*24 + colg*3)*16;
  u32x4* dst = (u32x4*)zb;
  #pragma unroll
  for (int q = 0; q < 3; ++q) {
    const int j0 = q*4;
    u32x4 s0 = { pk2(z0[j0],z1[j0]),     pk2(z2[j0],z3[j0]),
                 pk2(z0[j0+1],z1[j0+1]), pk2(z2[j0+1],z3[j0+1]) };
    u32x4 s1 = { pk2(z0[j0+2],z1[j0+2]), pk2(z2[j0+2],z3[j0+2]),
                 pk2(z0[j0+3],z1[j0+3]), pk2(z2[j0+3],z3[j0+3]) };
    dst[q*2]     = s0;
    dst[q*2 + 1] = s1;
  }
}

// ---------------- kernel B: out = ReLU(Wo'' @ z2 + co), bf16 MFMA, m97 structure -----------
__global__ __launch_bounds__(256) void kB(const void* __restrict__ wopp_,
    const void* __restrict__ z2s_, const float* __restrict__ co, float* __restrict__ out)
{
  __shared__ alignas(16) char lA[20480];
  __shared__ alignas(16) char lB[16384];
  const char* wopp = (const char*)wopp_;
  const char* z2s  = (const char*)z2s_;

  const int tid = threadIdx.x;
  const int lane = tid & 63, wv = tid >> 6;
  const int wm = wv >> 1, wn = wv & 1;
  const int pt = blockIdx.x;      // 0..71 pixel tiles
  const int mt = blockIdx.y;      // 0..3  oc tiles
  const int b  = blockIdx.z;      // 0..7
  const int pix0 = pt * 128;
  const int l15 = lane & 15, lg = lane >> 4;

  f32x4 acc[4][4] = {};

  for (int kt = 0; kt < 8; ++kt) {
    const char* srcA = wopp + (size_t)(mt*8 + kt)*20480;
    for (int j = wv; j < 20; j += 4)
      gll16(srcA + j*1024 + lane*16, lA + j*1024);
    #pragma unroll
    for (int ct4 = 0; ct4 < 4; ++ct4) {
      int ct = wv*4 + ct4;
      const char* srcB = z2s + ((size_t)(b*128 + kt*16 + ct)*36864 + (size_t)pix0*4)*2;
      gll16(srcB + lane*16, lB + ct*1024);
    }
    __syncthreads();

    #pragma unroll
    for (int kk = 0; kk < 2; ++kk) {
      s16x8 af[4];
      #pragma unroll
      for (int m = 0; m < 4; ++m)
        af[m] = *(const s16x8*)(lA + kk*10240 + (wm*64 + m*16 + l15)*80 + lg*16);
      #pragma unroll
      for (int n = 0; n < 4; ++n) {
        const char* p = lB + kk*8192 + lg*2048 + (wn*64 + n*16 + l15)*8;
        s16x4 lo = *(const s16x4*)(p);
        s16x4 hi = *(const s16x4*)(p + 1024);
        s16x8 bfr = __builtin_shufflevector(lo, hi, 0,1,2,3,4,5,6,7);
        #pragma unroll
        for (int m = 0; m < 4; ++m)
          acc[m][n] = __builtin_amdgcn_mfma_f32_16x16x32_bf16(af[m], bfr, acc[m][n], 0, 0, 0);
      }
    }
    __syncthreads();
  }

  const int colp = pix0 + wn*64 + l15;
  #pragma unroll
  for (int m = 0; m < 4; ++m) {
    const int ocb = mt*128 + wm*64 + m*16 + lg*4;
    #pragma unroll
    for (int r2 = 0; r2 < 4; ++r2) {
      const int oc = ocb + r2;
      const float cov = co[oc];
      float* orow = out + ((size_t)(b*512 + oc))*9216 + colp;
      #pragma unroll
      for (int n = 0; n < 4; ++n) {
        float v = acc[m][n][r2] + cov;
        orow[(size_t)n*16] = fmaxf(v, 0.f);
      }
    }
  }
}

extern "C" void kernel_launch(void* const* d_in, const int* in_sizes, int n_in,
                              void* d_out, int out_size, void* d_ws, size_t ws_size,
                              hipStream_t stream)
{
  (void)in_sizes; (void)out_size;
  if (n_in < 19) return;
  const size_t Z2_BYTES = 75497472;      // 8*512*9216 bf16
  const size_t WOPP_BYTES = 655360;      // 32 chunks * 20480
  if (ws_size < Z2_BYTES + WOPP_BYTES + 2048) return;

  const float* x    = (const float*)d_in[0];
  const float* wdw  = (const float*)d_in[1];
  const float* bdw  = (const float*)d_in[2];
  const float* gdw  = (const float*)d_in[3];
  const float* bedw = (const float*)d_in[4];
  const float* mdw  = (const float*)d_in[5];
  const float* vdw  = (const float*)d_in[6];
  const float* w4   = (const float*)d_in[7];
  const float* bs   = (const float*)d_in[8];
  const float* gs   = (const float*)d_in[9];
  const float* bes  = (const float*)d_in[10];
  const float* ms   = (const float*)d_in[11];
  const float* vs   = (const float*)d_in[12];
  const float* wo   = (const float*)d_in[13];
  const float* bo   = (const float*)d_in[14];
  const float* go   = (const float*)d_in[15];
  const float* beo  = (const float*)d_in[16];
  const float* mo   = (const float*)d_in[17];
  const float* vo   = (const float*)d_in[18];

  __bf16* z2s  = (__bf16*)d_ws;
  __bf16* wopp = (__bf16*)((char*)d_ws + Z2_BYTES);
  float*  co   = (float*)((char*)d_ws + Z2_BYTES + WOPP_BYTES);

  kF<<<512, 512, 0, stream>>>(wo, bo, go, beo, mo, vo, wopp, co);
  kA<<<1024, 768, 0, stream>>>(x, wdw, bdw, gdw, bedw, mdw, vdw, w4, bs, gs, bes, ms, vs, z2s);
  kB<<<dim3(72, 4, 8), 256, 0, stream>>>(wopp, z2s, co, (float*)d_out);
}

// Round 7
// 361.923 us; speedup vs baseline: 1.4013x; 1.4013x over previous
//
#include <hip/hip_runtime.h>
#include <cstdint>
#include <cstddef>

typedef float  f32x4 __attribute__((ext_vector_type(4)));
typedef float  f32x2 __attribute__((ext_vector_type(2)));
typedef short  s16x8 __attribute__((ext_vector_type(8)));
typedef short  s16x4 __attribute__((ext_vector_type(4)));
typedef unsigned int u32x4 __attribute__((ext_vector_type(4)));

#define EPSV 1e-5f

__device__ __forceinline__ float rfl(float v) {
  return __builtin_bit_cast(float, __builtin_amdgcn_readfirstlane(__builtin_bit_cast(int, v)));
}
__device__ __forceinline__ unsigned pk2(float a, float b) {
  unsigned short ua = __builtin_bit_cast(unsigned short, (__bf16)a);
  unsigned short ub = __builtin_bit_cast(unsigned short, (__bf16)b);
  return (unsigned)ua | ((unsigned)ub << 16);
}
__device__ __forceinline__ void gll16(const void* g, void* l) {
  __builtin_amdgcn_global_load_lds((const __attribute__((address_space(1))) unsigned int*)g,
                                   (__attribute__((address_space(3))) unsigned int*)l, 16, 0, 0);
}

// ---------------- kernel F: fold BN-o into Wo, emit bf16 in fragment layout ----------------
__global__ void kF(const float* __restrict__ wo, const float* __restrict__ bo,
                   const float* __restrict__ go, const float* __restrict__ beo,
                   const float* __restrict__ mo, const float* __restrict__ vo,
                   __bf16* __restrict__ wopp, float* __restrict__ co)
{
  const int oc = blockIdx.x;   // 0..511
  const int k  = threadIdx.x;  // 0..511
  float invo = go[oc] * rsqrtf(vo[oc] + EPSV);
  float v = wo[(size_t)oc*512 + k] * invo;
  int mt = oc >> 7, ocl = oc & 127;
  int kt = k >> 6, kk = (k >> 5) & 1, g = (k >> 3) & 3, jj = k & 7;
  size_t dst = (size_t)(mt*8 + kt)*10240 + (size_t)kk*5120 + ocl*40 + g*8 + jj;
  wopp[dst] = (__bf16)v;
  if (k == 0) co[oc] = bo[oc]*invo + beo[oc] - mo[oc]*invo;
}

// ---------------- kernel A: 4 dilated depthwise convs + BN + ReLU + 4x4 mix + BN + ReLU ----
// block = (b,c), full plane. LDS: 132 rows x 118 f32 (row = 18 zero-pad | 96 data | 4 zero
// slack), 18 zero rows top/bottom -> NO masks, NO range checks. Stride 118 == 22 mod 32
// dwords -> b64 reads at bank floor (R6 measured: conflicts 786K, down from 18.6M).
// __launch_bounds__(768,4): VGPR cap 128 -- live set ~110-120 (zacc 48 + acc 12 + windows).
// R6's (768,6) cap=85 spilled accumulators to scratch -> 1 GB HBM writes, 448 us. LDS limits
// occupancy to 2 blocks/CU regardless, so the higher cap costs nothing.
__global__ __launch_bounds__(768, 4) void kA(const float* __restrict__ x,
    const float* __restrict__ wdw, const float* __restrict__ bdw, const float* __restrict__ gdw,
    const float* __restrict__ bedw, const float* __restrict__ mdw, const float* __restrict__ vdw,
    const float* __restrict__ w4, const float* __restrict__ bsc, const float* __restrict__ gsc,
    const float* __restrict__ besc, const float* __restrict__ msc, const float* __restrict__ vsc,
    __bf16* __restrict__ z2s)
{
  __shared__ alignas(16) float sp[15596];       // 132*118 + 20 = 62384 B
  const int tid = threadIdx.x;
  const int b = blockIdx.x >> 7, c = blockIdx.x & 127;

  // uniform folded params (readfirstlane -> SGPRs)
  float wf[4][9], cdwv[4], w4f[4][4], c4v[4];
  #pragma unroll
  for (int i = 0; i < 4; ++i) {
    int idx = i*128 + c;
    float inv = gdw[idx] * rsqrtf(vdw[idx] + EPSV);
    #pragma unroll
    for (int t = 0; t < 9; ++t) wf[i][t] = rfl(wdw[(size_t)idx*9 + t] * inv);
    cdwv[i] = rfl(bdw[idx]*inv + bedw[idx] - mdw[idx]*inv);
  }
  #pragma unroll
  for (int o = 0; o < 4; ++o) {
    float invs = gsc[o] * rsqrtf(vsc[o] + EPSV);
    #pragma unroll
    for (int i = 0; i < 4; ++i) w4f[o][i] = rfl(w4[o*4 + i] * invs);
    c4v[o] = rfl(bsc[o]*invs + besc[o] - msc[o]*invs);
  }

  { // zero the whole buffer once (stage phases only write interior cols -> pads persist)
    f32x2* spv = (f32x2*)sp;
    #pragma unroll
    for (int z = 0; z < 11; ++z) {
      int idx = tid + z*768;
      if (idx < 7798) spv[idx] = (f32x2){0.f, 0.f};
    }
  }

  const int colg = tid & 7, row = tid >> 3;     // compute coords: 12 px, one row
  const int w0 = colg * 12;
  const int jc = tid % 24, jr = tid / 24;       // stage coords (rows jr, jr+32, jr+64)
  const f32x4* xv = (const f32x4*)x;
  const size_t gbase = (size_t)(b*512 + c) * 2304;

  float zacc[4][12];
  #pragma unroll
  for (int o = 0; o < 4; ++o)
    #pragma unroll
    for (int j = 0; j < 12; ++j) zacc[o][j] = c4v[o];

  const float* base = sp + row*118 + w0;        // min tap idx: row h-18 -> LDS row h

  const int RR[4] = {1, 6, 12, 18};
  #pragma unroll
  for (int i = 0; i < 4; ++i) {
    const int r = RR[i];
    __syncthreads();                            // buffer free (zero done / prev compute done)
    #pragma unroll
    for (int k = 0; k < 3; ++k) {               // stage plane i: 3 f32x4 per thread
      f32x4 v = xv[gbase + (size_t)i*294912 + (size_t)((jr + k*32)*24 + jc)];
      float* d = sp + (18 + jr + k*32)*118 + 18 + jc*4;   // 8B-aligned
      *(f32x2*)(d)     = (f32x2){v.x, v.y};
      *(f32x2*)(d + 2) = (f32x2){v.z, v.w};
    }
    __syncthreads();                            // plane ready

    float acc[12];
    #pragma unroll
    for (int j = 0; j < 12; ++j) acc[j] = 0.f;

    #pragma unroll
    for (int d = 0; d < 3; ++d) {               // dh = d-1; all offsets compile-time
      const int R0 = (18 + (d-1)*r)*118 + 18;   // rel f32 offset of col w0 at tap row
      const float wl = wf[i][d*3], wc = wf[i][d*3+1], wr = wf[i][d*3+2];
      if (i == 0) {                              // r=1: one 16-f32 span
        float s[16];
        #pragma unroll
        for (int t = 0; t < 8; ++t) *(f32x2*)(s + 2*t) = *(const f32x2*)(base + R0 - 2 + 2*t);
        #pragma unroll
        for (int j = 0; j < 12; ++j)
          acc[j] += wl*s[j+1] + wc*s[j+2] + wr*s[j+3];
      } else {                                   // even r: 3 disjoint 12-f32 windows, rolled
        float t[12];
        #pragma unroll
        for (int t2 = 0; t2 < 6; ++t2) *(f32x2*)(t + 2*t2) = *(const f32x2*)(base + R0 - r + 2*t2);
        #pragma unroll
        for (int j = 0; j < 12; ++j) acc[j] += wl*t[j];
        #pragma unroll
        for (int t2 = 0; t2 < 6; ++t2) *(f32x2*)(t + 2*t2) = *(const f32x2*)(base + R0 + 2*t2);
        #pragma unroll
        for (int j = 0; j < 12; ++j) acc[j] += wc*t[j];
        #pragma unroll
        for (int t2 = 0; t2 < 6; ++t2) *(f32x2*)(t + 2*t2) = *(const f32x2*)(base + R0 + r + 2*t2);
        #pragma unroll
        for (int j = 0; j < 12; ++j) acc[j] += wr*t[j];
      }
    }
    #pragma unroll
    for (int j = 0; j < 12; ++j) {
      float y = fmaxf(acc[j] + cdwv[i], 0.f);
      #pragma unroll
      for (int o = 0; o < 4; ++o) zacc[o][j] += w4f[o][i]*y;
    }
  }

  // finalize + store: [pix][o]; thread owns 3 quads = 96 B contiguous
  float z0[12], z1[12], z2[12], z3[12];
  #pragma unroll
  for (int j = 0; j < 12; ++j) {
    z0[j] = fmaxf(zacc[0][j], 0.f);
    z1[j] = fmaxf(zacc[1][j], 0.f);
    z2[j] = fmaxf(zacc[2][j], 0.f);
    z3[j] = fmaxf(zacc[3][j], 0.f);
  }
  __bf16* zb = z2s + (size_t)(b*128 + c)*36864 + (size_t)(row*24 + colg*3)*16;
  u32x4* dst = (u32x4*)zb;
  #pragma unroll
  for (int q = 0; q < 3; ++q) {
    const int j0 = q*4;
    u32x4 s0 = { pk2(z0[j0],z1[j0]),     pk2(z2[j0],z3[j0]),
                 pk2(z0[j0+1],z1[j0+1]), pk2(z2[j0+1],z3[j0+1]) };
    u32x4 s1 = { pk2(z0[j0+2],z1[j0+2]), pk2(z2[j0+2],z3[j0+2]),
                 pk2(z0[j0+3],z1[j0+3]), pk2(z2[j0+3],z3[j0+3]) };
    dst[q*2]     = s0;
    dst[q*2 + 1] = s1;
  }
}

// ---------------- kernel B: out = ReLU(Wo'' @ z2 + co), bf16 MFMA, m97 structure -----------
__global__ __launch_bounds__(256) void kB(const void* __restrict__ wopp_,
    const void* __restrict__ z2s_, const float* __restrict__ co, float* __restrict__ out)
{
  __shared__ alignas(16) char lA[20480];
  __shared__ alignas(16) char lB[16384];
  const char* wopp = (const char*)wopp_;
  const char* z2s  = (const char*)z2s_;

  const int tid = threadIdx.x;
  const int lane = tid & 63, wv = tid >> 6;
  const int wm = wv >> 1, wn = wv & 1;
  const int pt = blockIdx.x;      // 0..71 pixel tiles
  const int mt = blockIdx.y;      // 0..3  oc tiles
  const int b  = blockIdx.z;      // 0..7
  const int pix0 = pt * 128;
  const int l15 = lane & 15, lg = lane >> 4;

  f32x4 acc[4][4] = {};

  for (int kt = 0; kt < 8; ++kt) {
    const char* srcA = wopp + (size_t)(mt*8 + kt)*20480;
    for (int j = wv; j < 20; j += 4)
      gll16(srcA + j*1024 + lane*16, lA + j*1024);
    #pragma unroll
    for (int ct4 = 0; ct4 < 4; ++ct4) {
      int ct = wv*4 + ct4;
      const char* srcB = z2s + ((size_t)(b*128 + kt*16 + ct)*36864 + (size_t)pix0*4)*2;
      gll16(srcB + lane*16, lB + ct*1024);
    }
    __syncthreads();

    #pragma unroll
    for (int kk = 0; kk < 2; ++kk) {
      s16x8 af[4];
      #pragma unroll
      for (int m = 0; m < 4; ++m)
        af[m] = *(const s16x8*)(lA + kk*10240 + (wm*64 + m*16 + l15)*80 + lg*16);
      #pragma unroll
      for (int n = 0; n < 4; ++n) {
        const char* p = lB + kk*8192 + lg*2048 + (wn*64 + n*16 + l15)*8;
        s16x4 lo = *(const s16x4*)(p);
        s16x4 hi = *(const s16x4*)(p + 1024);
        s16x8 bfr = __builtin_shufflevector(lo, hi, 0,1,2,3,4,5,6,7);
        #pragma unroll
        for (int m = 0; m < 4; ++m)
          acc[m][n] = __builtin_amdgcn_mfma_f32_16x16x32_bf16(af[m], bfr, acc[m][n], 0, 0, 0);
      }
    }
    __syncthreads();
  }

  const int colp = pix0 + wn*64 + l15;
  #pragma unroll
  for (int m = 0; m < 4; ++m) {
    const int ocb = mt*128 + wm*64 + m*16 + lg*4;
    #pragma unroll
    for (int r2 = 0; r2 < 4; ++r2) {
      const int oc = ocb + r2;
      const float cov = co[oc];
      float* orow = out + ((size_t)(b*512 + oc))*9216 + colp;
      #pragma unroll
      for (int n = 0; n < 4; ++n) {
        float v = acc[m][n][r2] + cov;
        orow[(size_t)n*16] = fmaxf(v, 0.f);
      }
    }
  }
}

extern "C" void kernel_launch(void* const* d_in, const int* in_sizes, int n_in,
                              void* d_out, int out_size, void* d_ws, size_t ws_size,
                              hipStream_t stream)
{
  (void)in_sizes; (void)out_size;
  if (n_in < 19) return;
  const size_t Z2_BYTES = 75497472;      // 8*512*9216 bf16
  const size_t WOPP_BYTES = 655360;      // 32 chunks * 20480
  if (ws_size < Z2_BYTES + WOPP_BYTES + 2048) return;

  const float* x    = (const float*)d_in[0];
  const float* wdw  = (const float*)d_in[1];
  const float* bdw  = (const float*)d_in[2];
  const float* gdw  = (const float*)d_in[3];
  const float* bedw = (const float*)d_in[4];
  const float* mdw  = (const float*)d_in[5];
  const float* vdw  = (const float*)d_in[6];
  const float* w4   = (const float*)d_in[7];
  const float* bs   = (const float*)d_in[8];
  const float* gs   = (const float*)d_in[9];
  const float* bes  = (const float*)d_in[10];
  const float* ms   = (const float*)d_in[11];
  const float* vs   = (const float*)d_in[12];
  const float* wo   = (const float*)d_in[13];
  const float* bo   = (const float*)d_in[14];
  const float* go   = (const float*)d_in[15];
  const float* beo  = (const float*)d_in[16];
  const float* mo   = (const float*)d_in[17];
  const float* vo   = (const float*)d_in[18];

  __bf16* z2s  = (__bf16*)d_ws;
  __bf16* wopp = (__bf16*)((char*)d_ws + Z2_BYTES);
  float*  co   = (float*)((char*)d_ws + Z2_BYTES + WOPP_BYTES);

  kF<<<512, 512, 0, stream>>>(wo, bo, go, beo, mo, vo, wopp, co);
  kA<<<1024, 768, 0, stream>>>(x, wdw, bdw, gdw, bedw, mdw, vdw, w4, bs, gs, bes, ms, vs, z2s);
  kB<<<dim3(72, 4, 8), 256, 0, stream>>>(wopp, z2s, co, (float*)d_out);
}

// Round 8
// 247.752 us; speedup vs baseline: 2.0471x; 1.4608x over previous
//
#include <hip/hip_runtime.h>
#include <cstdint>
#include <cstddef>

typedef float  f32x4 __attribute__((ext_vector_type(4)));
typedef float  f32x2 __attribute__((ext_vector_type(2)));
typedef short  s16x8 __attribute__((ext_vector_type(8)));
typedef short  s16x4 __attribute__((ext_vector_type(4)));
typedef unsigned int u32x4 __attribute__((ext_vector_type(4)));

#define EPSV 1e-5f

__device__ __forceinline__ float rfl(float v) {
  return __builtin_bit_cast(float, __builtin_amdgcn_readfirstlane(__builtin_bit_cast(int, v)));
}
__device__ __forceinline__ unsigned pk2(float a, float b) {
  unsigned short ua = __builtin_bit_cast(unsigned short, (__bf16)a);
  unsigned short ub = __builtin_bit_cast(unsigned short, (__bf16)b);
  return (unsigned)ua | ((unsigned)ub << 16);
}
__device__ __forceinline__ void gll16(const void* g, void* l) {
  __builtin_amdgcn_global_load_lds((const __attribute__((address_space(1))) unsigned int*)g,
                                   (__attribute__((address_space(3))) unsigned int*)l, 16, 0, 0);
}

// ---------------- kernel F: fold BN-o into Wo, emit bf16 in fragment layout ----------------
__global__ void kF(const float* __restrict__ wo, const float* __restrict__ bo,
                   const float* __restrict__ go, const float* __restrict__ beo,
                   const float* __restrict__ mo, const float* __restrict__ vo,
                   __bf16* __restrict__ wopp, float* __restrict__ co)
{
  const int oc = blockIdx.x;   // 0..511
  const int k  = threadIdx.x;  // 0..511
  float invo = go[oc] * rsqrtf(vo[oc] + EPSV);
  float v = wo[(size_t)oc*512 + k] * invo;
  int mt = oc >> 7, ocl = oc & 127;
  int kt = k >> 6, kk = (k >> 5) & 1, g = (k >> 3) & 3, jj = k & 7;
  size_t dst = (size_t)(mt*8 + kt)*10240 + (size_t)kk*5120 + ocl*40 + g*8 + jj;
  wopp[dst] = (__bf16)v;
  if (k == 0) co[oc] = bo[oc]*invo + beo[oc] - mo[oc]*invo;
}

// ---------------- kernel A: 4 dilated depthwise convs + BN + ReLU + 4x4 mix + BN + ReLU ----
// block = (b,c), full plane. LDS: 132 rows x 118 f32 (row = 18 zero-pad | 96 data | 4 slack),
// 18 zero rows top/bottom -> NO masks, NO range checks. Stride 118 == 22 mod 32 dwords ->
// b64 reads conflict-free (R6 measured: 786K, 24x below R5).
// CRITICAL (R6/R7 lesson): no type-punned local arrays. All windows/accumulators are native
// f32x2 arrays with compile-time indices -> SROA promotes to VGPRs; punned float[] went to
// scratch (R7: 0.86 GB of spill traffic, 320 us).
__global__ __launch_bounds__(768, 4) void kA(const float* __restrict__ x,
    const float* __restrict__ wdw, const float* __restrict__ bdw, const float* __restrict__ gdw,
    const float* __restrict__ bedw, const float* __restrict__ mdw, const float* __restrict__ vdw,
    const float* __restrict__ w4, const float* __restrict__ bsc, const float* __restrict__ gsc,
    const float* __restrict__ besc, const float* __restrict__ msc, const float* __restrict__ vsc,
    __bf16* __restrict__ z2s)
{
  __shared__ alignas(16) float sp[15596];       // 132*118 + 20 = 62384 B
  const int tid = threadIdx.x;
  const int b = blockIdx.x >> 7, c = blockIdx.x & 127;

  // uniform folded params (readfirstlane -> SGPRs)
  float wf[4][9], cdwv[4], w4f[4][4], c4v[4];
  #pragma unroll
  for (int i = 0; i < 4; ++i) {
    int idx = i*128 + c;
    float inv = gdw[idx] * rsqrtf(vdw[idx] + EPSV);
    #pragma unroll
    for (int t = 0; t < 9; ++t) wf[i][t] = rfl(wdw[(size_t)idx*9 + t] * inv);
    cdwv[i] = rfl(bdw[idx]*inv + bedw[idx] - mdw[idx]*inv);
  }
  #pragma unroll
  for (int o = 0; o < 4; ++o) {
    float invs = gsc[o] * rsqrtf(vsc[o] + EPSV);
    #pragma unroll
    for (int i = 0; i < 4; ++i) w4f[o][i] = rfl(w4[o*4 + i] * invs);
    c4v[o] = rfl(bsc[o]*invs + besc[o] - msc[o]*invs);
  }

  { // zero the whole buffer once (stage phases only write interior cols -> pads persist)
    f32x2* spv = (f32x2*)sp;
    #pragma unroll
    for (int z = 0; z < 11; ++z) {
      int idx = tid + z*768;
      if (idx < 7798) spv[idx] = (f32x2){0.f, 0.f};
    }
  }

  const int colg = tid & 7, row = tid >> 3;     // compute coords: 12 px, one row
  const int w0 = colg * 12;
  const int jc = tid % 24, jr = tid / 24;       // stage coords (rows jr, jr+32, jr+64)
  const f32x4* xv = (const f32x4*)x;
  const size_t gbase = (size_t)(b*512 + c) * 2304;

  f32x2 zacc[4][6];
  #pragma unroll
  for (int o = 0; o < 4; ++o)
    #pragma unroll
    for (int k = 0; k < 6; ++k) zacc[o][k] = (f32x2){c4v[o], c4v[o]};

  const float* base = sp + row*118 + w0;        // LDS row (row+18) = global row `row`... via R0

  const int RR[4] = {1, 6, 12, 18};
  #pragma unroll
  for (int i = 0; i < 4; ++i) {
    const int r = RR[i];
    __syncthreads();                            // buffer free (zero done / prev compute done)
    #pragma unroll
    for (int k = 0; k < 3; ++k) {               // stage plane i: 3 f32x4 per thread
      f32x4 v = xv[gbase + (size_t)i*294912 + (size_t)((jr + k*32)*24 + jc)];
      float* d = sp + (18 + jr + k*32)*118 + 18 + jc*4;   // 8B-aligned
      *(f32x2*)(d)     = (f32x2){v.x, v.y};
      *(f32x2*)(d + 2) = (f32x2){v.z, v.w};
    }
    __syncthreads();                            // plane ready

    f32x2 acc[6];
    #pragma unroll
    for (int k = 0; k < 6; ++k) acc[k] = (f32x2){0.f, 0.f};

    #pragma unroll
    for (int d = 0; d < 3; ++d) {               // dh = d-1; all ds offsets compile-time
      const int R0 = (18 + (d-1)*r)*118 + 18;   // rel f32 offset of col w0 at tap row
      const float wl = wf[i][d*3], wc = wf[i][d*3+1], wr = wf[i][d*3+2];
      if (i == 0) {                              // r=1: span [w0-2, w0+14) = 8 native f32x2
        f32x2 s[8];
        #pragma unroll
        for (int t = 0; t < 8; ++t) s[t] = *(const f32x2*)(base + R0 - 2 + 2*t);
        #pragma unroll
        for (int j = 0; j < 12; ++j) {
          const float tl = ((j+1)&1) ? s[(j+1)>>1].y : s[(j+1)>>1].x;
          const float tc = ((j+2)&1) ? s[(j+2)>>1].y : s[(j+2)>>1].x;
          const float tr = ((j+3)&1) ? s[(j+3)>>1].y : s[(j+3)>>1].x;
          const float a = wl*tl + wc*tc + wr*tr;
          if (j&1) acc[j>>1].y += a; else acc[j>>1].x += a;
        }
      } else {                                   // even r: 3 windows of 6 native f32x2, rolled
        f32x2 t[6];
        #pragma unroll
        for (int k = 0; k < 6; ++k) t[k] = *(const f32x2*)(base + R0 - r + 2*k);
        #pragma unroll
        for (int k = 0; k < 6; ++k) acc[k] += wl * t[k];
        #pragma unroll
        for (int k = 0; k < 6; ++k) t[k] = *(const f32x2*)(base + R0 + 2*k);
        #pragma unroll
        for (int k = 0; k < 6; ++k) acc[k] += wc * t[k];
        #pragma unroll
        for (int k = 0; k < 6; ++k) t[k] = *(const f32x2*)(base + R0 + r + 2*k);
        #pragma unroll
        for (int k = 0; k < 6; ++k) acc[k] += wr * t[k];
      }
    }
    #pragma unroll
    for (int k = 0; k < 6; ++k) {
      f32x2 y;
      y.x = fmaxf(acc[k].x + cdwv[i], 0.f);
      y.y = fmaxf(acc[k].y + cdwv[i], 0.f);
      #pragma unroll
      for (int o = 0; o < 4; ++o) zacc[o][k] += w4f[o][i] * y;
    }
  }

  // finalize + store: [pix][o]; thread owns 3 quads = 96 B contiguous
#define ZG(o, j) fmaxf(((j)&1) ? zacc[o][(j)>>1].y : zacc[o][(j)>>1].x, 0.f)
  __bf16* zb = z2s + (size_t)(b*128 + c)*36864 + (size_t)(row*24 + colg*3)*16;
  u32x4* dst = (u32x4*)zb;
  #pragma unroll
  for (int q = 0; q < 3; ++q) {
    const int j0 = q*4;
    u32x4 s0 = { pk2(ZG(0,j0),  ZG(1,j0)),   pk2(ZG(2,j0),  ZG(3,j0)),
                 pk2(ZG(0,j0+1),ZG(1,j0+1)), pk2(ZG(2,j0+1),ZG(3,j0+1)) };
    u32x4 s1 = { pk2(ZG(0,j0+2),ZG(1,j0+2)), pk2(ZG(2,j0+2),ZG(3,j0+2)),
                 pk2(ZG(0,j0+3),ZG(1,j0+3)), pk2(ZG(2,j0+3),ZG(3,j0+3)) };
    dst[q*2]     = s0;
    dst[q*2 + 1] = s1;
  }
#undef ZG
}

// ---------------- kernel B: out = ReLU(Wo'' @ z2 + co), bf16 MFMA, m97 structure -----------
__global__ __launch_bounds__(256) void kB(const void* __restrict__ wopp_,
    const void* __restrict__ z2s_, const float* __restrict__ co, float* __restrict__ out)
{
  __shared__ alignas(16) char lA[20480];
  __shared__ alignas(16) char lB[16384];
  const char* wopp = (const char*)wopp_;
  const char* z2s  = (const char*)z2s_;

  const int tid = threadIdx.x;
  const int lane = tid & 63, wv = tid >> 6;
  const int wm = wv >> 1, wn = wv & 1;
  const int pt = blockIdx.x;      // 0..71 pixel tiles
  const int mt = blockIdx.y;      // 0..3  oc tiles
  const int b  = blockIdx.z;      // 0..7
  const int pix0 = pt * 128;
  const int l15 = lane & 15, lg = lane >> 4;

  f32x4 acc[4][4] = {};

  for (int kt = 0; kt < 8; ++kt) {
    const char* srcA = wopp + (size_t)(mt*8 + kt)*20480;
    for (int j = wv; j < 20; j += 4)
      gll16(srcA + j*1024 + lane*16, lA + j*1024);
    #pragma unroll
    for (int ct4 = 0; ct4 < 4; ++ct4) {
      int ct = wv*4 + ct4;
      const char* srcB = z2s + ((size_t)(b*128 + kt*16 + ct)*36864 + (size_t)pix0*4)*2;
      gll16(srcB + lane*16, lB + ct*1024);
    }
    __syncthreads();

    #pragma unroll
    for (int kk = 0; kk < 2; ++kk) {
      s16x8 af[4];
      #pragma unroll
      for (int m = 0; m < 4; ++m)
        af[m] = *(const s16x8*)(lA + kk*10240 + (wm*64 + m*16 + l15)*80 + lg*16);
      #pragma unroll
      for (int n = 0; n < 4; ++n) {
        const char* p = lB + kk*8192 + lg*2048 + (wn*64 + n*16 + l15)*8;
        s16x4 lo = *(const s16x4*)(p);
        s16x4 hi = *(const s16x4*)(p + 1024);
        s16x8 bfr = __builtin_shufflevector(lo, hi, 0,1,2,3,4,5,6,7);
        #pragma unroll
        for (int m = 0; m < 4; ++m)
          acc[m][n] = __builtin_amdgcn_mfma_f32_16x16x32_bf16(af[m], bfr, acc[m][n], 0, 0, 0);
      }
    }
    __syncthreads();
  }

  const int colp = pix0 + wn*64 + l15;
  #pragma unroll
  for (int m = 0; m < 4; ++m) {
    const int ocb = mt*128 + wm*64 + m*16 + lg*4;
    #pragma unroll
    for (int r2 = 0; r2 < 4; ++r2) {
      const int oc = ocb + r2;
      const float cov = co[oc];
      float* orow = out + ((size_t)(b*512 + oc))*9216 + colp;
      #pragma unroll
      for (int n = 0; n < 4; ++n) {
        float v = acc[m][n][r2] + cov;
        orow[(size_t)n*16] = fmaxf(v, 0.f);
      }
    }
  }
}

extern "C" void kernel_launch(void* const* d_in, const int* in_sizes, int n_in,
                              void* d_out, int out_size, void* d_ws, size_t ws_size,
                              hipStream_t stream)
{
  (void)in_sizes; (void)out_size;
  if (n_in < 19) return;
  const size_t Z2_BYTES = 75497472;      // 8*512*9216 bf16
  const size_t WOPP_BYTES = 655360;      // 32 chunks * 20480
  if (ws_size < Z2_BYTES + WOPP_BYTES + 2048) return;

  const float* x    = (const float*)d_in[0];
  const float* wdw  = (const float*)d_in[1];
  const float* bdw  = (const float*)d_in[2];
  const float* gdw  = (const float*)d_in[3];
  const float* bedw = (const float*)d_in[4];
  const float* mdw  = (const float*)d_in[5];
  const float* vdw  = (const float*)d_in[6];
  const float* w4   = (const float*)d_in[7];
  const float* bs   = (const float*)d_in[8];
  const float* gs   = (const float*)d_in[9];
  const float* bes  = (const float*)d_in[10];
  const float* ms   = (const float*)d_in[11];
  const float* vs   = (const float*)d_in[12];
  const float* wo   = (const float*)d_in[13];
  const float* bo   = (const float*)d_in[14];
  const float* go   = (const float*)d_in[15];
  const float* beo  = (const float*)d_in[16];
  const float* mo   = (const float*)d_in[17];
  const float* vo   = (const float*)d_in[18];

  __bf16* z2s  = (__bf16*)d_ws;
  __bf16* wopp = (__bf16*)((char*)d_ws + Z2_BYTES);
  float*  co   = (float*)((char*)d_ws + Z2_BYTES + WOPP_BYTES);

  kF<<<512, 512, 0, stream>>>(wo, bo, go, beo, mo, vo, wopp, co);
  kA<<<1024, 768, 0, stream>>>(x, wdw, bdw, gdw, bedw, mdw, vdw, w4, bs, gs, bes, ms, vs, z2s);
  kB<<<dim3(72, 4, 8), 256, 0, stream>>>(wopp, z2s, co, (float*)d_out);
}